// Round 1
// baseline (18541.045 us; speedup 1.0000x reference)
//
#include <hip/hip_runtime.h>
#include <hip/hip_fp16.h>
#include <stdint.h>

// TBRNN: x_{t+1} = x + 0.05*n_t + 0.2*(-x + rec(r) + inp_t), r = tanh(x)
// rec[b,i] = sum_{j,k} r[b,j] * w_hh[i,j,k] * r[b,k]
// B=16, T=512, I=8, H=256

#define NOISE_STD 0.05f
#define TAU 0.2f

typedef _Float16 f16x8 __attribute__((ext_vector_type(8)));
typedef float f32x4 __attribute__((ext_vector_type(4)));

__device__ __forceinline__ float fast_tanh(float x){
  float cx = fminf(fmaxf(x, -10.f), 10.f);
  float e = __expf(2.f*cx);
  return 1.f - 2.f*__builtin_amdgcn_rcpf(e + 1.f);
}

// ---- zero rec buffers (4 x 16KB) + barrier counters (ws is poisoned 0xAA) ----
__global__ void init_ws(float* recbufs, unsigned* bar){
  int t = threadIdx.x;
  #pragma unroll
  for (int c = 0; c < 64; ++c) recbufs[c*256 + t] = 0.f;
  #pragma unroll
  for (int c = 0; c < 4; ++c) bar[c*256 + t] = 0u;
}

// ---- inp[t][b][h] = sum_i u[b][t][i]*w_in_w[h][i] + w_in_b[h] ----
__global__ void inp_kernel(const float* __restrict__ u, const float* __restrict__ w_in_w,
                           const float* __restrict__ w_in_b, float* __restrict__ inp){
  int F = blockIdx.x*256 + threadIdx.x;      // < 2097152, [t][b][h]
  int h = F & 255; int b = (F>>8) & 15; int t = F >> 12;
  const float* up = u + (b*512 + t)*8;
  const float* wp = w_in_w + h*8;
  float s = w_in_b[h];
  #pragma unroll
  for (int i = 0; i < 8; ++i) s += up[i]*wp[i];
  inp[F] = s;
}

// ---- swizzle w_hh (fp32 [i][j][k]) into fp16 MFMA-B-fragment order ----
// layout: [nt][kc][w][s][lane][e], s = kk*4+jl ; i = nt*16+(lane&15),
// j = kc*16 + w*4 + (s&3), k = (s>>2)*32 + (lane>>4)*8 + e
__global__ void wsw_kernel(const float* __restrict__ w_hh, __half* __restrict__ wsw){
  int F = blockIdx.x*256 + threadIdx.x;      // < 16777216
  int e = F & 7, lane = (F>>3)&63, s = (F>>9)&31, w = (F>>14)&3, kc = (F>>16)&15, nt = F>>20;
  int i = nt*16 + (lane & 15);
  int j = kc*16 + w*4 + (s & 3);
  int k = (s>>2)*32 + (lane>>4)*8 + e;
  wsw[F] = __float2half(w_hh[(i<<16) | (j<<8) | k]);
}

// ---- persistent recurrence kernel: 256 blocks x 256 threads, cooperative ----
// block bid: nt = bid&15 (i-tile of 16), kc = bid>>4 (j-chunk of 16)
// W slice lives in 128 VGPRs/lane for the whole kernel.
__global__ void __launch_bounds__(256, 1) rnn_kernel(
    const float* __restrict__ x0, const float* __restrict__ noise,
    const float* __restrict__ inp, const __half* __restrict__ wsw,
    float* recbufs, unsigned* bar, float* __restrict__ traj, float* __restrict__ xlast)
{
  __shared__ float x_lds[4096];        // x[b][h] fp32, full state per block
  __shared__ __half r_lds[16*260];     // tanh(x), row stride 260 (bank-safe, 8B aligned)
  __shared__ float red[1024];          // cross-wave reduce

  const int tid = threadIdx.x;
  const int bid = blockIdx.x;
  const int wv = tid >> 6, lane = tid & 63;
  const int q = lane >> 4, col = lane & 15;
  const int nt = bid & 15, kc = bid >> 4;
  const int jb = kc*16 + wv*4;

  unsigned* gcnt = bar;               // 16 group counters, stride 32 u32 (128B apart)
  unsigned* top  = bar + 520;
  unsigned* gen  = bar + 536;

  // ---- load W fragments into registers once (32KB per wave) ----
  uint4 wreg[8][4];
  {
    const uint4* gw = (const uint4*)wsw + (size_t)(((nt*16 + kc)*4 + wv)*32)*64 + lane;
    #pragma unroll
    for (int kk = 0; kk < 8; ++kk)
      #pragma unroll
      for (int jl = 0; jl < 4; ++jl)
        wreg[kk][jl] = gw[(kk*4 + jl)*64];
  }

  // ---- init state ----
  #pragma unroll
  for (int c = 0; c < 16; ++c){
    int f = c*256 + tid;
    float xv = x0[f];
    x_lds[f] = xv;
    r_lds[c*260 + tid] = __float2half(fast_tanh(xv));
  }
  __syncthreads();

  #pragma unroll 1
  for (int t = 0; t < 512; ++t){
    float* rb = recbufs + (t & 3)*4096;

    // ---- phase 1: GEMM  rec[b, nt*16..+16) partial over j in [kc*16..+16) ----
    // A[b=col][k] = r[col][j] * r[col][k] built via v_pk_mul_f16; B from wreg.
    f32x4 acc = {0.f, 0.f, 0.f, 0.f};
    #pragma unroll
    for (int kk = 0; kk < 8; ++kk){
      const __half2* rkp = (const __half2*)&r_lds[col*260 + kk*32 + q*8];
      __half2 rk0 = rkp[0], rk1 = rkp[1], rk2 = rkp[2], rk3 = rkp[3];
      #pragma unroll
      for (int jl = 0; jl < 4; ++jl){
        __half2 rj2 = __half2half2(r_lds[col*260 + jb + jl]);
        union { __half2 h2[4]; f16x8 v; } au;
        au.h2[0] = __hmul2(rj2, rk0);
        au.h2[1] = __hmul2(rj2, rk1);
        au.h2[2] = __hmul2(rj2, rk2);
        au.h2[3] = __hmul2(rj2, rk3);
        union { uint4 u; f16x8 v; } wu; wu.u = wreg[kk][jl];
        acc = __builtin_amdgcn_mfma_f32_16x16x32_f16(au.v, wu.v, acc, 0, 0, 0);
      }
    }

    // ---- reduce 4 waves in LDS, one device-scope atomicAdd per thread ----
    // D layout: row(b) = q*4+r, col(iLocal) = lane&15
    #pragma unroll
    for (int r = 0; r < 4; ++r) red[wv*256 + (q*4 + r)*16 + col] = acc[r];
    __syncthreads();
    {
      float v = red[tid] + red[256 + tid] + red[512 + tid] + red[768 + tid];
      atomicAdd(&rb[(tid>>4)*256 + nt*16 + (tid & 15)], v);
    }

    // prefetch noise/inp for this step (independent of rec; overlaps barrier)
    const float* np = noise + t*4096;
    const float* ip = inp + t*4096;
    float nv[16], iv[16];
    #pragma unroll
    for (int c = 0; c < 16; ++c){ nv[c] = np[c*256 + tid]; iv[c] = ip[c*256 + tid]; }

    // ---- grid barrier (two-level, monotonic counters, agent scope) ----
    __threadfence();
    __syncthreads();
    if (tid == 0){
      int g = bid >> 4;
      unsigned prev = __hip_atomic_fetch_add(&gcnt[g*32], 1u, __ATOMIC_ACQ_REL, __HIP_MEMORY_SCOPE_AGENT);
      if (prev == (unsigned)(t*16 + 15)){
        unsigned pt = __hip_atomic_fetch_add(top, 1u, __ATOMIC_ACQ_REL, __HIP_MEMORY_SCOPE_AGENT);
        if (pt == (unsigned)(t*16 + 15))
          __hip_atomic_store(gen, (unsigned)(t + 1), __ATOMIC_RELEASE, __HIP_MEMORY_SCOPE_AGENT);
      }
      while (__hip_atomic_load(gen, __ATOMIC_ACQUIRE, __HIP_MEMORY_SCOPE_AGENT) < (unsigned)(t + 1))
        __builtin_amdgcn_s_sleep(1);
    }
    __syncthreads();

    // ---- phase 3: state update (redundant per block, block-local LDS state) ----
    #pragma unroll
    for (int c = 0; c < 16; ++c){
      int f = c*256 + tid;             // b = c, h = tid
      float rec = __hip_atomic_load(&rb[f], __ATOMIC_RELAXED, __HIP_MEMORY_SCOPE_AGENT);
      float xo = x_lds[f];
      float xn = xo + NOISE_STD*nv[c] + TAU*(rec + iv[c] - xo);
      x_lds[f] = xn;
      r_lds[c*260 + tid] = __float2half(fast_tanh(xn));
      if (bid < 16 && c == bid) traj[(size_t)bid*131072 + t*256 + tid] = xn;
    }
    // zero slot t+2 (separated from its use by the next barrier)
    if (tid < 16)
      __hip_atomic_store(&recbufs[((t + 2) & 3)*4096 + bid*16 + tid], 0.f,
                         __ATOMIC_RELAXED, __HIP_MEMORY_SCOPE_AGENT);
    __syncthreads();
  }
  if (bid < 16) xlast[bid*256 + tid] = x_lds[bid*256 + tid];
}

// ---- out[b][t][o] = sum_h tanh(traj[b][t][h]) * w_out_w[o][h] + w_out_b[o] ----
__global__ void out_kernel(const float* __restrict__ traj, const float* __restrict__ w_out_w,
                           const float* __restrict__ w_out_b, float* __restrict__ out){
  __shared__ float wo[2048];
  int tid = threadIdx.x;
  #pragma unroll
  for (int c = 0; c < 8; ++c) wo[c*256 + tid] = w_out_w[c*256 + tid];
  __syncthreads();
  int wv = tid >> 6, lane = tid & 63;
  int p = blockIdx.x*4 + wv;                 // p = b*512 + t, < 8192
  float4 v = *(const float4*)&traj[(size_t)p*256 + lane*4];
  float th0 = fast_tanh(v.x), th1 = fast_tanh(v.y), th2 = fast_tanh(v.z), th3 = fast_tanh(v.w);
  #pragma unroll
  for (int o = 0; o < 8; ++o){
    const float* w = &wo[o*256 + lane*4];
    float s = th0*w[0] + th1*w[1] + th2*w[2] + th3*w[3];
    #pragma unroll
    for (int off = 32; off > 0; off >>= 1) s += __shfl_xor(s, off, 64);
    if (lane == 0) out[(size_t)p*8 + o] = s + w_out_b[o];
  }
}

extern "C" void kernel_launch(void* const* d_in, const int* in_sizes, int n_in,
                              void* d_out, int out_size, void* d_ws, size_t ws_size,
                              hipStream_t stream){
  const float* u       = (const float*)d_in[0];
  const float* x0      = (const float*)d_in[1];
  const float* noise   = (const float*)d_in[2];
  const float* w_hh    = (const float*)d_in[3];
  const float* w_in_w  = (const float*)d_in[4];
  const float* w_in_b  = (const float*)d_in[5];
  const float* w_out_w = (const float*)d_in[6];
  const float* w_out_b = (const float*)d_in[7];

  float* out   = (float*)d_out;          // [16][512][8]   = 65536
  float* xlast = out + 65536;            // [16][256]      = 4096
  float* traj  = xlast + 4096;           // [16][512][256] = 2097152

  uint8_t* ws = (uint8_t*)d_ws;
  float*    recbufs = (float*)ws;                       // 64 KiB (4 slots x 4096 f32)
  unsigned* bar     = (unsigned*)(ws + 65536);          // 4 KiB barrier counters
  float*    inp     = (float*)(ws + 69632);             // 8 MiB  [T][B][H]
  __half*   wsw     = (__half*)(ws + 69632 + 8388608);  // 32 MiB swizzled W (fp16)

  init_ws<<<1, 256, 0, stream>>>(recbufs, bar);
  inp_kernel<<<8192, 256, 0, stream>>>(u, w_in_w, w_in_b, inp);
  wsw_kernel<<<65536, 256, 0, stream>>>(w_hh, wsw);
  {
    void* args[] = {(void*)&x0, (void*)&noise, (void*)&inp, (void*)&wsw,
                    (void*)&recbufs, (void*)&bar, (void*)&traj, (void*)&xlast};
    hipLaunchCooperativeKernel((const void*)rnn_kernel, dim3(256), dim3(256),
                               args, 0, stream);
  }
  out_kernel<<<2048, 256, 0, stream>>>(traj, w_out_w, w_out_b, out);
}

// Round 2
// 4816.744 us; speedup vs baseline: 3.8493x; 3.8493x over previous
//
#include <hip/hip_runtime.h>
#include <hip/hip_fp16.h>
#include <stdint.h>

// TBRNN: x_{t+1} = x + 0.05*n_t + 0.2*(-x + rec(r) + inp_t), r = tanh(x)
// rec[b,i] = sum_{j,k} r[b,j] * w_hh[i,j,k] * r[b,k]
// B=16, T=512, I=8, H=256
//
// Split: one i per block (256 blocks). W[i] lives in 128 VGPRs/wave
// (wave wv owns j-tiles wv*4..wv*4+3). Per step:
//   stage1 (MFMA): tmp[b][j] = sum_k W[i][j][k] r[b][k]   (A = r, no packing)
//   stage2 (VALU): rec[b]    = sum_j r[b][j] tmp[b][j]
// Block writes rec[b][i] (16 floats, [b][i] layout -> coalesced reader) via
// agent-scope relaxed atomic stores (sc0/sc1, bypass non-coherent L2), then
// one relaxed fetch_add on its group counter. Readers poll 16 counters with
// RELAXED agent loads: no buffer_inv / buffer_wbl2 anywhere in the loop.

#define NOISE_STD 0.05f
#define TAU 0.2f

typedef _Float16 f16x8 __attribute__((ext_vector_type(8)));
typedef float f32x4 __attribute__((ext_vector_type(4)));

__device__ __forceinline__ float fast_tanh(float x){
  float cx = fminf(fmaxf(x, -10.f), 10.f);
  float e = __expf(2.f*cx);
  return 1.f - 2.f*__builtin_amdgcn_rcpf(e + 1.f);
}

// ---- zero barrier counters (ws is poisoned 0xAA) ----
__global__ void init_ws(unsigned* bar){
  int t = threadIdx.x;
  #pragma unroll
  for (int c = 0; c < 4; ++c) bar[c*256 + t] = 0u;
}

// ---- pre[t][b][h] = NOISE_STD*noise + TAU*(u@w_in^T + b_in) ----
__global__ void pre_kernel(const float* __restrict__ u, const float* __restrict__ noise,
                           const float* __restrict__ w_in_w, const float* __restrict__ w_in_b,
                           float* __restrict__ pre){
  int F = blockIdx.x*256 + threadIdx.x;      // < 2097152, [t][b][h]
  int h = F & 255; int b = (F>>8) & 15; int t = F >> 12;
  const float* up = u + (b*512 + t)*8;
  const float* wp = w_in_w + h*8;
  float s = w_in_b[h];
  #pragma unroll
  for (int i = 0; i < 8; ++i) s += up[i]*wp[i];
  pre[F] = NOISE_STD*noise[F] + TAU*s;
}

// ---- swizzle w_hh (fp32 [i][j][k]) into fp16 MFMA-B-fragment order ----
// uint4 index = ((i*4 + wv)*32 + jtl*8 + ks)*64 + lane, element e in 0..7
// B[k][n=j]: j = (wv*4+jtl)*16 + (lane&15), k = ks*32 + (lane>>4)*8 + e
__global__ void wsw_kernel(const float* __restrict__ w_hh, __half* __restrict__ wsw){
  int F = blockIdx.x*256 + threadIdx.x;      // < 16777216
  int e = F & 7, lane = (F>>3)&63, ks = (F>>9)&7, jtl = (F>>12)&3, wv = (F>>14)&3, i = F>>16;
  int j = (wv*4 + jtl)*16 + (lane & 15);
  int k = ks*32 + (lane>>4)*8 + e;
  wsw[F] = __float2half(w_hh[(i<<16) | (j<<8) | k]);
}

// ---- persistent recurrence kernel: 256 blocks x 256 threads, cooperative ----
__global__ void __launch_bounds__(256, 1) rnn_kernel(
    const float* __restrict__ x0, const float* __restrict__ pre, const __half* __restrict__ wsw,
    float* recG, unsigned* bar, float* __restrict__ traj, float* __restrict__ xlast)
{
  __shared__ alignas(16) float x_lds[4096];       // x[b][h] fp32
  __shared__ alignas(16) __half r_lds[16*264];    // r[b][k] fp16, row stride 264 (16B-aligned)
  __shared__ float red[64];                        // cross-wave rec reduce

  const int tid = threadIdx.x;
  const int bid = blockIdx.x;                      // = i
  const int wv = tid >> 6, lane = tid & 63;
  const int q = lane >> 4, col = lane & 15;

  // ---- load W[i] fragments into registers once (32KB per wave) ----
  uint4 wreg[4][8];
  {
    const uint4* gw = (const uint4*)wsw + (size_t)(bid*4 + wv)*32*64 + lane;
    #pragma unroll
    for (int jtl = 0; jtl < 4; ++jtl)
      #pragma unroll
      for (int ks = 0; ks < 8; ++ks)
        wreg[jtl][ks] = gw[(jtl*8 + ks)*64];
  }

  // ---- init state ----
  #pragma unroll
  for (int c = 0; c < 16; ++c){
    int f = c*256 + tid;
    float xv = x0[f];
    x_lds[f] = xv;
    r_lds[c*264 + tid] = __float2half(fast_tanh(xv));
  }
  __syncthreads();

  #pragma unroll 1
  for (int t = 0; t < 512; ++t){
    float* rb = recG + (t & 3)*4096;

    // prefetch fused noise+input term (consumed after the barrier)
    float pv[16];
    {
      const float* pp = pre + t*4096;
      #pragma unroll
      for (int c = 0; c < 16; ++c) pv[c] = pp[c*256 + tid];
    }

    // ---- stage 1: tmp[b][j] = sum_k W[i][j][k] r[b][k]  (wave's 4 j-tiles) ----
    f32x4 acc[4] = {{0.f,0.f,0.f,0.f},{0.f,0.f,0.f,0.f},{0.f,0.f,0.f,0.f},{0.f,0.f,0.f,0.f}};
    #pragma unroll
    for (int ks = 0; ks < 8; ++ks){
      f16x8 A = *(const f16x8*)&r_lds[col*264 + ks*32 + q*8];   // A[b=col][k-frag]
      #pragma unroll
      for (int jtl = 0; jtl < 4; ++jtl){
        union { uint4 u; f16x8 v; } wu; wu.u = wreg[jtl][ks];
        acc[jtl] = __builtin_amdgcn_mfma_f32_16x16x32_f16(A, wu.v, acc[jtl], 0, 0, 0);
      }
    }

    // ---- stage 2: rec[b] partial = sum_j r[b][j]*tmp[b][j] over wave's j's ----
    // D layout: col(j) = lane&15, row(b) = q*4 + reg
    float s[4] = {0.f, 0.f, 0.f, 0.f};
    #pragma unroll
    for (int jtl = 0; jtl < 4; ++jtl){
      int j = (wv*4 + jtl)*16 + col;
      #pragma unroll
      for (int reg = 0; reg < 4; ++reg)
        s[reg] += acc[jtl][reg] * __half2float(r_lds[(q*4 + reg)*264 + j]);
    }
    #pragma unroll
    for (int off = 1; off < 16; off <<= 1){
      #pragma unroll
      for (int reg = 0; reg < 4; ++reg) s[reg] += __shfl_xor(s[reg], off, 64);
    }
    if (col == 0){
      #pragma unroll
      for (int reg = 0; reg < 4; ++reg) red[wv*16 + q*4 + reg] = s[reg];
    }
    __syncthreads();

    // ---- publish rec[b][i] (complete values, no atomics/reduction) ----
    if (tid < 16){
      float v = red[tid] + red[16 + tid] + red[32 + tid] + red[48 + tid];
      __hip_atomic_store(&rb[tid*256 + bid], v, __ATOMIC_RELAXED, __HIP_MEMORY_SCOPE_AGENT);
    }
    asm volatile("s_waitcnt vmcnt(0)" ::: "memory");
    if (tid == 0)
      __hip_atomic_fetch_add(&bar[(bid >> 4)*32], 1u, __ATOMIC_RELAXED, __HIP_MEMORY_SCOPE_AGENT);

    // ---- poll 16 group counters with RELAXED agent loads (no cache inv) ----
    if (tid < 16){
      unsigned target = (unsigned)(t + 1)*16u;
      while (__hip_atomic_load(&bar[tid*32], __ATOMIC_RELAXED, __HIP_MEMORY_SCOPE_AGENT) < target)
        __builtin_amdgcn_s_sleep(1);
    }
    __syncthreads();

    // ---- state update (redundant per block, block-local LDS state) ----
    #pragma unroll
    for (int c = 0; c < 16; ++c){
      int f = c*256 + tid;             // b = c, h = tid
      float rec = __hip_atomic_load(&rb[f], __ATOMIC_RELAXED, __HIP_MEMORY_SCOPE_AGENT);
      float xo = x_lds[f];
      float xn = xo + TAU*(rec - xo) + pv[c];
      x_lds[f] = xn;
      r_lds[c*264 + tid] = __float2half(fast_tanh(xn));
      if (bid < 16 && c == bid) traj[(size_t)bid*131072 + t*256 + tid] = xn;
    }
    __syncthreads();
  }
  if (bid < 16) xlast[bid*256 + tid] = x_lds[bid*256 + tid];
}

// ---- out[b][t][o] = sum_h tanh(traj[b][t][h]) * w_out_w[o][h] + w_out_b[o] ----
__global__ void out_kernel(const float* __restrict__ traj, const float* __restrict__ w_out_w,
                           const float* __restrict__ w_out_b, float* __restrict__ out){
  __shared__ float wo[2048];
  int tid = threadIdx.x;
  #pragma unroll
  for (int c = 0; c < 8; ++c) wo[c*256 + tid] = w_out_w[c*256 + tid];
  __syncthreads();
  int wv = tid >> 6, lane = tid & 63;
  int p = blockIdx.x*4 + wv;                 // p = b*512 + t, < 8192
  float4 v = *(const float4*)&traj[(size_t)p*256 + lane*4];
  float th0 = fast_tanh(v.x), th1 = fast_tanh(v.y), th2 = fast_tanh(v.z), th3 = fast_tanh(v.w);
  #pragma unroll
  for (int o = 0; o < 8; ++o){
    const float* w = &wo[o*256 + lane*4];
    float s = th0*w[0] + th1*w[1] + th2*w[2] + th3*w[3];
    #pragma unroll
    for (int off = 32; off > 0; off >>= 1) s += __shfl_xor(s, off, 64);
    if (lane == 0) out[(size_t)p*8 + o] = s + w_out_b[o];
  }
}

extern "C" void kernel_launch(void* const* d_in, const int* in_sizes, int n_in,
                              void* d_out, int out_size, void* d_ws, size_t ws_size,
                              hipStream_t stream){
  const float* u       = (const float*)d_in[0];
  const float* x0      = (const float*)d_in[1];
  const float* noise   = (const float*)d_in[2];
  const float* w_hh    = (const float*)d_in[3];
  const float* w_in_w  = (const float*)d_in[4];
  const float* w_in_b  = (const float*)d_in[5];
  const float* w_out_w = (const float*)d_in[6];
  const float* w_out_b = (const float*)d_in[7];

  float* out   = (float*)d_out;          // [16][512][8]   = 65536
  float* xlast = out + 65536;            // [16][256]      = 4096
  float* traj  = xlast + 4096;           // [16][512][256] = 2097152

  uint8_t* ws = (uint8_t*)d_ws;
  float*    recG = (float*)ws;                        // 64 KiB (4 slots x 4096 f32, [b][i])
  unsigned* bar  = (unsigned*)(ws + 65536);           // 4 KiB barrier counters (16, stride 32 u32)
  float*    pre  = (float*)(ws + 69632);              // 8 MiB  [T][B][H] fused noise+input
  __half*   wsw  = (__half*)(ws + 69632 + 8388608);   // 32 MiB swizzled W (fp16)

  init_ws<<<1, 256, 0, stream>>>(bar);
  pre_kernel<<<8192, 256, 0, stream>>>(u, noise, w_in_w, w_in_b, pre);
  wsw_kernel<<<65536, 256, 0, stream>>>(w_hh, wsw);
  {
    void* args[] = {(void*)&x0, (void*)&pre, (void*)&wsw,
                    (void*)&recG, (void*)&bar, (void*)&traj, (void*)&xlast};
    hipLaunchCooperativeKernel((const void*)rnn_kernel, dim3(256), dim3(256),
                               args, 0, stream);
  }
  out_kernel<<<2048, 256, 0, stream>>>(traj, w_out_w, w_out_b, out);
}

// Round 3
// 2916.012 us; speedup vs baseline: 6.3584x; 1.6518x over previous
//
#include <hip/hip_runtime.h>
#include <hip/hip_fp16.h>
#include <stdint.h>

// TBRNN: x_{t+1} = x + 0.05*n_t + 0.2*(-x + rec(r) + inp_t), r = tanh(x)
// rec[b,i] = sum_{j,k} r[b,j] * w_hh[i,j,k] * r[b,k];  B=16, T=512, I=8, H=256
//
// Ownership split: block i owns x[b][i] (16 floats, registers of lanes 0..15).
// Per step, block i computes rec[b][i] via MFMA (W[i] register-resident,
// 128 VGPRs/wave), updates its x slice, publishes r[b][i] = tanh(x) as fp16
// (32 B, one coherent store), bumps a group counter, polls 16 counters with
// relaxed agent loads, then reads the full r[16][256] slot (8 KB) with TWO
// pipelined global_load_dwordx4 sc0 sc1 per thread -> LDS. No atomics on the
// data path, no per-element serialized latency.

#define NOISE_STD 0.05f
#define TAU 0.2f

typedef _Float16 f16x8 __attribute__((ext_vector_type(8)));
typedef float f32x4 __attribute__((ext_vector_type(4)));
typedef unsigned int u32x4 __attribute__((ext_vector_type(4)));

__device__ __forceinline__ float fast_tanh(float x){
  float cx = fminf(fmaxf(x, -10.f), 10.f);
  float e = __expf(2.f*cx);
  return 1.f - 2.f*__builtin_amdgcn_rcpf(e + 1.f);
}

// ---- zero barrier counters (ws is poisoned 0xAA) ----
__global__ void init_ws(unsigned* bar){
  int t = threadIdx.x;
  #pragma unroll
  for (int c = 0; c < 4; ++c) bar[c*256 + t] = 0u;
}

// ---- pre[t][h][b] = NOISE_STD*noise[t][b][h] + TAU*(u@w_in^T + b_in)[b][h] ----
__global__ void pre_kernel(const float* __restrict__ u, const float* __restrict__ noise,
                           const float* __restrict__ w_in_w, const float* __restrict__ w_in_b,
                           float* __restrict__ pre){
  int F = blockIdx.x*256 + threadIdx.x;      // < 2097152, [t][h][b]
  int b = F & 15; int h = (F>>4) & 255; int t = F >> 12;
  const float* up = u + (b*512 + t)*8;
  const float* wp = w_in_w + h*8;
  float s = w_in_b[h];
  #pragma unroll
  for (int i = 0; i < 8; ++i) s += up[i]*wp[i];
  pre[F] = NOISE_STD*noise[t*4096 + b*256 + h] + TAU*s;
}

// ---- swizzle w_hh (fp32 [i][j][k]) into fp16 MFMA-B-fragment order ----
// uint4 index = ((i*4 + wv)*32 + jtl*8 + ks)*64 + lane, element e in 0..7
// B[k][n=j]: j = (wv*4+jtl)*16 + (lane&15), k = ks*32 + (lane>>4)*8 + e
__global__ void wsw_kernel(const float* __restrict__ w_hh, __half* __restrict__ wsw){
  int F = blockIdx.x*256 + threadIdx.x;      // < 16777216
  int e = F & 7, lane = (F>>3)&63, ks = (F>>9)&7, jtl = (F>>12)&3, wv = (F>>14)&3, i = F>>16;
  int j = (wv*4 + jtl)*16 + (lane & 15);
  int k = ks*32 + (lane>>4)*8 + e;
  wsw[F] = __float2half(w_hh[(i<<16) | (j<<8) | k]);
}

// ---- persistent recurrence kernel: 256 blocks x 256 threads, cooperative ----
__global__ void __launch_bounds__(256, 1) rnn_kernel(
    const float* __restrict__ x0, const float* __restrict__ pre, const __half* __restrict__ wsw,
    __half* rG, unsigned* bar, float* __restrict__ traj, float* __restrict__ xlast)
{
  __shared__ alignas(16) __half r_lds[16*264];    // r[b][k] fp16, row stride 264
  __shared__ float red[64];                        // cross-wave rec reduce

  const int tid = threadIdx.x;
  const int bid = blockIdx.x;                      // = i
  const int wv = tid >> 6, lane = tid & 63;
  const int q = lane >> 4, col = lane & 15;

  // ---- load W[i] fragments into registers once (32KB per wave) ----
  uint4 wreg[4][8];
  {
    const uint4* gw = (const uint4*)wsw + (size_t)(bid*4 + wv)*32*64 + lane;
    #pragma unroll
    for (int jtl = 0; jtl < 4; ++jtl)
      #pragma unroll
      for (int ks = 0; ks < 8; ++ks)
        wreg[jtl][ks] = gw[(jtl*8 + ks)*64];
  }

  // ---- init: x slice in registers (lanes 0..15), full r in LDS ----
  float xreg = 0.f;
  if (tid < 16) xreg = x0[tid*256 + bid];
  #pragma unroll
  for (int c = 0; c < 16; ++c)
    r_lds[c*264 + tid] = __float2half(fast_tanh(x0[c*256 + tid]));
  __syncthreads();

  #pragma unroll 1
  for (int t = 0; t < 512; ++t){
    __half* rb = rG + (t & 3)*4096;

    // fused noise+input term for this block's slice (one 64B transaction)
    float pv = 0.f;
    if (tid < 16) pv = pre[t*4096 + bid*16 + tid];

    // ---- stage 1: tmp[b][j] = sum_k W[i][j][k] r[b][k] ----
    f32x4 acc[4] = {{0.f,0.f,0.f,0.f},{0.f,0.f,0.f,0.f},{0.f,0.f,0.f,0.f},{0.f,0.f,0.f,0.f}};
    #pragma unroll
    for (int ks = 0; ks < 8; ++ks){
      f16x8 A = *(const f16x8*)&r_lds[col*264 + ks*32 + q*8];   // A[b=col][k-frag]
      #pragma unroll
      for (int jtl = 0; jtl < 4; ++jtl){
        union { uint4 u; f16x8 v; } wu; wu.u = wreg[jtl][ks];
        acc[jtl] = __builtin_amdgcn_mfma_f32_16x16x32_f16(A, wu.v, acc[jtl], 0, 0, 0);
      }
    }

    // ---- stage 2: rec[b] partial = sum_j r[b][j]*tmp[b][j] ----
    // D layout: col(j) = lane&15, row(b) = q*4 + reg
    float s[4] = {0.f, 0.f, 0.f, 0.f};
    #pragma unroll
    for (int jtl = 0; jtl < 4; ++jtl){
      int j = (wv*4 + jtl)*16 + col;
      #pragma unroll
      for (int reg = 0; reg < 4; ++reg)
        s[reg] += acc[jtl][reg] * __half2float(r_lds[(q*4 + reg)*264 + j]);
    }
    #pragma unroll
    for (int off = 1; off < 16; off <<= 1){
      #pragma unroll
      for (int reg = 0; reg < 4; ++reg) s[reg] += __shfl_xor(s[reg], off, 64);
    }
    if (col == 0){
      #pragma unroll
      for (int reg = 0; reg < 4; ++reg) red[wv*16 + q*4 + reg] = s[reg];
    }
    __syncthreads();

    // ---- owner lanes: update x slice, publish r slice (fp16, 32B total) ----
    float xn = 0.f;
    if (tid < 16){
      float rec = red[tid] + red[16 + tid] + red[32 + tid] + red[48 + tid];
      xn = xreg + TAU*(rec - xreg) + pv;
      xreg = xn;
      unsigned rv = (unsigned)__half_as_ushort(__float2half(fast_tanh(xn)));
      asm volatile("global_store_short %0, %1, off sc0 sc1"
                   :: "v"(&rb[tid*256 + bid]), "v"(rv) : "memory");
    }
    asm volatile("s_waitcnt vmcnt(0)" ::: "memory");
    if (tid == 0)
      __hip_atomic_fetch_add(&bar[(bid >> 4)*32], 1u, __ATOMIC_RELAXED, __HIP_MEMORY_SCOPE_AGENT);
    if (tid < 16)
      traj[(size_t)tid*131072 + t*256 + bid] = xn;   // off the barrier path

    // ---- poll 16 group counters (relaxed agent loads, no cache maintenance) ----
    if (tid < 16){
      unsigned target = (unsigned)(t + 1)*16u;
      while (__hip_atomic_load(&bar[tid*32], __ATOMIC_RELAXED, __HIP_MEMORY_SCOPE_AGENT) < target)
        __builtin_amdgcn_s_sleep(1);
    }
    __syncthreads();

    // ---- read full r slot (8KB): two pipelined coherent 16B loads/thread ----
    {
      const u32x4* p0 = (const u32x4*)rb + tid;        // halfs [tid*8 .. +8)
      const u32x4* p1 = p0 + 256;
      u32x4 ra, rc;
      asm volatile("global_load_dwordx4 %0, %2, off sc0 sc1\n\t"
                   "global_load_dwordx4 %1, %3, off sc0 sc1\n\t"
                   "s_waitcnt vmcnt(0)"
                   : "=&v"(ra), "=&v"(rc)
                   : "v"(p0), "v"(p1) : "memory");
      // u32x4 idx covers halfs [idx*8..+8): b = idx>>5, k = (idx&31)*8
      *(u32x4*)&r_lds[(tid>>5)*264 + (tid&31)*8] = ra;
      *(u32x4*)&r_lds[((tid>>5) + 8)*264 + (tid&31)*8] = rc;
    }
    __syncthreads();
  }
  if (tid < 16) xlast[tid*256 + bid] = xreg;
}

// ---- out[b][t][o] = sum_h tanh(traj[b][t][h]) * w_out_w[o][h] + w_out_b[o] ----
__global__ void out_kernel(const float* __restrict__ traj, const float* __restrict__ w_out_w,
                           const float* __restrict__ w_out_b, float* __restrict__ out){
  __shared__ float wo[2048];
  int tid = threadIdx.x;
  #pragma unroll
  for (int c = 0; c < 8; ++c) wo[c*256 + tid] = w_out_w[c*256 + tid];
  __syncthreads();
  int wv = tid >> 6, lane = tid & 63;
  int p = blockIdx.x*4 + wv;                 // p = b*512 + t, < 8192
  float4 v = *(const float4*)&traj[(size_t)p*256 + lane*4];
  float th0 = fast_tanh(v.x), th1 = fast_tanh(v.y), th2 = fast_tanh(v.z), th3 = fast_tanh(v.w);
  #pragma unroll
  for (int o = 0; o < 8; ++o){
    const float* w = &wo[o*256 + lane*4];
    float s = th0*w[0] + th1*w[1] + th2*w[2] + th3*w[3];
    #pragma unroll
    for (int off = 32; off > 0; off >>= 1) s += __shfl_xor(s, off, 64);
    if (lane == 0) out[(size_t)p*8 + o] = s + w_out_b[o];
  }
}

extern "C" void kernel_launch(void* const* d_in, const int* in_sizes, int n_in,
                              void* d_out, int out_size, void* d_ws, size_t ws_size,
                              hipStream_t stream){
  const float* u       = (const float*)d_in[0];
  const float* x0      = (const float*)d_in[1];
  const float* noise   = (const float*)d_in[2];
  const float* w_hh    = (const float*)d_in[3];
  const float* w_in_w  = (const float*)d_in[4];
  const float* w_in_b  = (const float*)d_in[5];
  const float* w_out_w = (const float*)d_in[6];
  const float* w_out_b = (const float*)d_in[7];

  float* out   = (float*)d_out;          // [16][512][8]   = 65536
  float* xlast = out + 65536;            // [16][256]      = 4096
  float* traj  = xlast + 4096;           // [16][512][256] = 2097152

  uint8_t* ws = (uint8_t*)d_ws;
  __half*   rG  = (__half*)ws;                        // 32 KiB (4 slots x 4096 fp16, [b][i])
  unsigned* bar = (unsigned*)(ws + 32768);            // 4 KiB barrier counters (16, stride 32 u32)
  float*    pre = (float*)(ws + 36864);               // 8 MiB  [T][H][B] fused noise+input
  __half*   wsw = (__half*)(ws + 36864 + 8388608);    // 32 MiB swizzled W (fp16)

  init_ws<<<1, 256, 0, stream>>>(bar);
  pre_kernel<<<8192, 256, 0, stream>>>(u, noise, w_in_w, w_in_b, pre);
  wsw_kernel<<<65536, 256, 0, stream>>>(w_hh, wsw);
  {
    void* args[] = {(void*)&x0, (void*)&pre, (void*)&wsw,
                    (void*)&rG, (void*)&bar, (void*)&traj, (void*)&xlast};
    hipLaunchCooperativeKernel((const void*)rnn_kernel, dim3(256), dim3(256),
                               args, 0, stream);
  }
  out_kernel<<<2048, 256, 0, stream>>>(traj, w_out_w, w_out_b, out);
}

// Round 4
// 1827.906 us; speedup vs baseline: 10.1433x; 1.5953x over previous
//
#include <hip/hip_runtime.h>
#include <hip/hip_fp16.h>
#include <stdint.h>

// TBRNN: x_{t+1} = x + 0.05*n_t + 0.2*(-x + rec(r) + inp_t), r = tanh(x)
// rec[b,i] = sum_{j,k} r[b,j] * w_hh[i,j,k] * r[b,k];  B=16, T=512, I=8, H=256
//
// Dataflow sync (no barrier): 512 unique publication slots xG[t][i][b] (fp16),
// pre-filled with sentinel 0xFFFF (NaN; never produced by __float2half of a
// finite x). Block i owns x[b][i] (lanes 0..15), computes rec via MFMA with
// W[i] register-resident (128 VGPRs/wave), publishes fp16 x_{t+1} as ONE
// coalesced 32B store, then every thread polls its two 16B chunks of slot t
// until sentinel-free (data IS the flag; single-writer slots make any
// visibility interleaving safe). Pollers compute r=tanh(x) and transpose into
// LDS. Max inter-block spread is structurally 1 step; no acks, no counters,
// no cache-maintenance ops anywhere in the loop.

#define NOISE_STD 0.05f
#define TAU 0.2f

typedef _Float16 f16x8 __attribute__((ext_vector_type(8)));
typedef float f32x4 __attribute__((ext_vector_type(4)));
typedef unsigned int u32x4 __attribute__((ext_vector_type(4)));

__device__ __forceinline__ float fast_tanh(float x){
  float cx = fminf(fmaxf(x, -10.f), 10.f);
  float e = __expf(2.f*cx);
  return 1.f - 2.f*__builtin_amdgcn_rcpf(e + 1.f);
}

// ---- fill xG (4 MiB = 1,048,576 dwords) with fp16 sentinel 0xFFFF ----
__global__ void fill_sentinel(unsigned* p){
  p[blockIdx.x*256u + threadIdx.x] = 0xFFFFFFFFu;
}

// ---- pre2[h][t][b] = NOISE_STD*noise[t][b][h] + TAU*(u@w_in^T + b_in)[b][h] ----
__global__ void pre_kernel(const float* __restrict__ u, const float* __restrict__ noise,
                           const float* __restrict__ w_in_w, const float* __restrict__ w_in_b,
                           float* __restrict__ pre2){
  int F = blockIdx.x*256 + threadIdx.x;      // < 2097152, enumerated [t][h][b]
  int b = F & 15; int h = (F>>4) & 255; int t = F >> 12;
  const float* up = u + (b*512 + t)*8;
  const float* wp = w_in_w + h*8;
  float s = w_in_b[h];
  #pragma unroll
  for (int i = 0; i < 8; ++i) s += up[i]*wp[i];
  pre2[h*8192 + t*16 + b] = NOISE_STD*noise[t*4096 + b*256 + h] + TAU*s;
}

// ---- swizzle w_hh (fp32 [i][j][k]) into fp16 MFMA-B-fragment order ----
// uint4 index = ((i*4 + wv)*32 + jtl*8 + ks)*64 + lane, element e in 0..7
// B[k][n=j]: j = (wv*4+jtl)*16 + (lane&15), k = ks*32 + (lane>>4)*8 + e
__global__ void wsw_kernel(const float* __restrict__ w_hh, __half* __restrict__ wsw){
  int F = blockIdx.x*256 + threadIdx.x;      // < 16777216
  int e = F & 7, lane = (F>>3)&63, ks = (F>>9)&7, jtl = (F>>12)&3, wv = (F>>14)&3, i = F>>16;
  int j = (wv*4 + jtl)*16 + (lane & 15);
  int k = ks*32 + (lane>>4)*8 + e;
  wsw[F] = __float2half(w_hh[(i<<16) | (j<<8) | k]);
}

// ---- persistent recurrence kernel: 256 blocks x 256 threads, cooperative ----
__global__ void __launch_bounds__(256, 1) rnn_kernel(
    const float* __restrict__ x0, const float* __restrict__ pre2, const __half* __restrict__ wsw,
    __half* xG, float* __restrict__ traj, float* __restrict__ xlast)
{
  __shared__ alignas(16) unsigned short r_lds[16*264];  // r[b][k] fp16 bits
  __shared__ alignas(16) unsigned short x_lds[16*264];  // x[b][h] fp16 bits
  __shared__ alignas(16) float pre_lds[8192];           // pre2 slice [t][b_own]
  __shared__ float red[64];

  const int tid = threadIdx.x;
  const int bid = blockIdx.x;                      // = i
  const int wv = tid >> 6, lane = tid & 63;
  const int q = lane >> 4, col = lane & 15;

  // ---- load W[i] fragments into registers once (32KB per wave) ----
  uint4 wreg[4][8];
  {
    const uint4* gw = (const uint4*)wsw + (size_t)(bid*4 + wv)*32*64 + lane;
    #pragma unroll
    for (int jtl = 0; jtl < 4; ++jtl)
      #pragma unroll
      for (int ks = 0; ks < 8; ++ks)
        wreg[jtl][ks] = gw[(jtl*8 + ks)*64];
  }

  // ---- pre slice (512 steps x 16 b = 32KB) -> LDS, fully coalesced ----
  {
    const float4* ps = (const float4*)(pre2 + bid*8192);
    float4* pl = (float4*)pre_lds;
    #pragma unroll
    for (int c = 0; c < 8; ++c) pl[c*256 + tid] = ps[c*256 + tid];
  }

  // ---- init: x slice in registers (lanes 0..15), r_0 in LDS ----
  float xreg = 0.f;
  if (tid < 16) xreg = x0[tid*256 + bid];
  #pragma unroll
  for (int c = 0; c < 16; ++c)
    r_lds[c*264 + tid] = __half_as_ushort(__float2half(fast_tanh(x0[c*256 + tid])));
  __syncthreads();

  const int i0 = tid >> 1, bb = (tid & 1)*8;       // poll-chunk coords
  const int tb = bid >> 4, th = (bid & 15)*16;     // this block's traj slice

  #pragma unroll 1
  for (int t = 0; t < 512; ++t){
    // traj for step t-1 (x_lds holds x_t): balanced 64B coalesced store
    if (t > 0 && tid < 16)
      traj[(size_t)tb*131072 + (t-1)*256 + th + tid] =
        __half2float(__ushort_as_half(x_lds[tb*264 + th + tid]));

    float pv = 0.f;
    if (tid < 16) pv = pre_lds[t*16 + tid];

    // ---- stage 1: tmp[b][j] = sum_k W[i][j][k] r[b][k] ----
    f32x4 acc[4] = {{0.f,0.f,0.f,0.f},{0.f,0.f,0.f,0.f},{0.f,0.f,0.f,0.f},{0.f,0.f,0.f,0.f}};
    #pragma unroll
    for (int ks = 0; ks < 8; ++ks){
      f16x8 A = *(const f16x8*)(r_lds + col*264 + ks*32 + q*8);   // A[b=col][k-frag]
      #pragma unroll
      for (int jtl = 0; jtl < 4; ++jtl){
        union { uint4 u; f16x8 v; } wu; wu.u = wreg[jtl][ks];
        acc[jtl] = __builtin_amdgcn_mfma_f32_16x16x32_f16(A, wu.v, acc[jtl], 0, 0, 0);
      }
    }

    // ---- stage 2: rec[b] partial = sum_j r[b][j]*tmp[b][j] ----
    float s[4] = {0.f, 0.f, 0.f, 0.f};
    #pragma unroll
    for (int jtl = 0; jtl < 4; ++jtl){
      int j = (wv*4 + jtl)*16 + col;
      #pragma unroll
      for (int reg = 0; reg < 4; ++reg)
        s[reg] += acc[jtl][reg] * __half2float(__ushort_as_half(r_lds[(q*4 + reg)*264 + j]));
    }
    #pragma unroll
    for (int off = 1; off < 16; off <<= 1){
      #pragma unroll
      for (int reg = 0; reg < 4; ++reg) s[reg] += __shfl_xor(s[reg], off, 64);
    }
    if (col == 0){
      #pragma unroll
      for (int reg = 0; reg < 4; ++reg) red[wv*16 + q*4 + reg] = s[reg];
    }
    __syncthreads();

    // ---- owners: update x, publish fp16 x (32B contiguous, fire-and-forget) ----
    if (tid < 16){
      float rec = red[tid] + red[16 + tid] + red[32 + tid] + red[48 + tid];
      float xn = xreg + TAU*(rec - xreg) + pv;
      xreg = xn;
      unsigned xv = (unsigned)__half_as_ushort(__float2half(xn));
      asm volatile("global_store_short %0, %1, off sc0 sc1"
                   :: "v"(xG + (size_t)t*4096 + bid*16 + tid), "v"(xv) : "memory");
    }

    // ---- poll slot t (data-as-flag), transpose x->r into LDS ----
    {
      const u32x4* base = (const u32x4*)(xG + (size_t)t*4096);
      const u32x4* p0 = base + tid;
      const u32x4* p1 = base + tid + 256;
      u32x4 ra, rc;
      bool ok0 = false, ok1 = false;
      do {
        if (!ok0) asm volatile("global_load_dwordx4 %0, %1, off sc0 sc1"
                               : "=v"(ra) : "v"(p0) : "memory");
        if (!ok1) asm volatile("global_load_dwordx4 %0, %1, off sc0 sc1"
                               : "=v"(rc) : "v"(p1) : "memory");
        asm volatile("s_waitcnt vmcnt(0)" ::: "memory");
        if (!ok0) ok0 = !((ra.x & 0xFFFFu)==0xFFFFu || (ra.x>>16)==0xFFFFu ||
                          (ra.y & 0xFFFFu)==0xFFFFu || (ra.y>>16)==0xFFFFu ||
                          (ra.z & 0xFFFFu)==0xFFFFu || (ra.z>>16)==0xFFFFu ||
                          (ra.w & 0xFFFFu)==0xFFFFu || (ra.w>>16)==0xFFFFu);
        if (!ok1) ok1 = !((rc.x & 0xFFFFu)==0xFFFFu || (rc.x>>16)==0xFFFFu ||
                          (rc.y & 0xFFFFu)==0xFFFFu || (rc.y>>16)==0xFFFFu ||
                          (rc.z & 0xFFFFu)==0xFFFFu || (rc.z>>16)==0xFFFFu ||
                          (rc.w & 0xFFFFu)==0xFFFFu || (rc.w>>16)==0xFFFFu);
      } while (!(ok0 && ok1));

      union { u32x4 v; unsigned short h[8]; } ua, uc;
      ua.v = ra; uc.v = rc;
      #pragma unroll
      for (int m = 0; m < 8; ++m){
        unsigned short xa = ua.h[m], xb = uc.h[m];
        r_lds[(bb+m)*264 + i0] =
          __half_as_ushort(__float2half(fast_tanh(__half2float(__ushort_as_half(xa)))));
        r_lds[(bb+m)*264 + i0 + 128] =
          __half_as_ushort(__float2half(fast_tanh(__half2float(__ushort_as_half(xb)))));
        x_lds[(bb+m)*264 + i0]       = xa;
        x_lds[(bb+m)*264 + i0 + 128] = xb;
      }
    }
    __syncthreads();
  }

  if (tid < 16){
    traj[(size_t)tb*131072 + 511*256 + th + tid] =
      __half2float(__ushort_as_half(x_lds[tb*264 + th + tid]));
    xlast[tid*256 + bid] = xreg;
  }
}

// ---- out[b][t][o] = sum_h tanh(traj[b][t][h]) * w_out_w[o][h] + w_out_b[o] ----
__global__ void out_kernel(const float* __restrict__ traj, const float* __restrict__ w_out_w,
                           const float* __restrict__ w_out_b, float* __restrict__ out){
  __shared__ float wo[2048];
  int tid = threadIdx.x;
  #pragma unroll
  for (int c = 0; c < 8; ++c) wo[c*256 + tid] = w_out_w[c*256 + tid];
  __syncthreads();
  int wv = tid >> 6, lane = tid & 63;
  int p = blockIdx.x*4 + wv;                 // p = b*512 + t, < 8192
  float4 v = *(const float4*)&traj[(size_t)p*256 + lane*4];
  float th0 = fast_tanh(v.x), th1 = fast_tanh(v.y), th2 = fast_tanh(v.z), th3 = fast_tanh(v.w);
  #pragma unroll
  for (int o = 0; o < 8; ++o){
    const float* w = &wo[o*256 + lane*4];
    float s = th0*w[0] + th1*w[1] + th2*w[2] + th3*w[3];
    #pragma unroll
    for (int off = 32; off > 0; off >>= 1) s += __shfl_xor(s, off, 64);
    if (lane == 0) out[(size_t)p*8 + o] = s + w_out_b[o];
  }
}

extern "C" void kernel_launch(void* const* d_in, const int* in_sizes, int n_in,
                              void* d_out, int out_size, void* d_ws, size_t ws_size,
                              hipStream_t stream){
  const float* u       = (const float*)d_in[0];
  const float* x0      = (const float*)d_in[1];
  const float* noise   = (const float*)d_in[2];
  const float* w_hh    = (const float*)d_in[3];
  const float* w_in_w  = (const float*)d_in[4];
  const float* w_in_b  = (const float*)d_in[5];
  const float* w_out_w = (const float*)d_in[6];
  const float* w_out_b = (const float*)d_in[7];

  float* out   = (float*)d_out;          // [16][512][8]   = 65536
  float* xlast = out + 65536;            // [16][256]      = 4096
  float* traj  = xlast + 4096;           // [16][512][256] = 2097152

  uint8_t* ws = (uint8_t*)d_ws;
  __half* xG   = (__half*)ws;                          // 4 MiB: 512 slots x [i][b] fp16
  float*  pre2 = (float*)(ws + 4194304);               // 8 MiB: [h][t][b]
  __half* wsw  = (__half*)(ws + 4194304 + 8388608);    // 32 MiB swizzled W (fp16)

  fill_sentinel<<<4096, 256, 0, stream>>>((unsigned*)xG);
  pre_kernel<<<8192, 256, 0, stream>>>(u, noise, w_in_w, w_in_b, pre2);
  wsw_kernel<<<65536, 256, 0, stream>>>(w_hh, wsw);
  {
    void* args[] = {(void*)&x0, (void*)&pre2, (void*)&wsw,
                    (void*)&xG, (void*)&traj, (void*)&xlast};
    hipLaunchCooperativeKernel((const void*)rnn_kernel, dim3(256), dim3(256),
                               args, 0, stream);
  }
  out_kernel<<<2048, 256, 0, stream>>>(traj, w_out_w, w_out_b, out);
}

// Round 5
// 1813.752 us; speedup vs baseline: 10.2225x; 1.0078x over previous
//
#include <hip/hip_runtime.h>
#include <hip/hip_fp16.h>
#include <stdint.h>

// TBRNN: x_{t+1} = x + 0.05*n_t + 0.2*(-x + rec(r) + inp_t), r = tanh(x)
// rec[b,i] = sum_{j,k} r[b,j] * w_hh[i,j,k] * r[b,k];  B=16, T=512, I=8, H=256
//
// Round 5 structure:
//  - block i owns x[b][i]; W[i] register-resident (128 VGPRs/lane).
//  - publishes r=tanh(x_{t+1}) fp16 (32 B line, sc0 sc1, fire-and-forget).
//  - WAVE SPLIT: wave0 = owner/publisher (never waits vmcnt); waves 2-3 = pollers
//    (no outstanding stores on their waves -> vmcnt(0) is loads-only).
//  - raw `s_waitcnt lgkmcnt(0); s_barrier` instead of __syncthreads (no vmcnt(0)
//    store-drain on the critical path).
//  - data-as-flag: slot t pre-filled with fp16 sentinel 0xFFFF (NaN, never equals
//    tanh output); single-writer write-once slots make any visibility order safe.
//  - consumer transform = conflict-free ds_write_b32 transpose (no tanh).
//  - owners write traj fp32 directly (scatter, off critical path).

#define NOISE_STD 0.05f
#define TAU 0.2f

typedef _Float16 f16x8 __attribute__((ext_vector_type(8)));
typedef float f32x4 __attribute__((ext_vector_type(4)));
typedef unsigned int u32x4 __attribute__((ext_vector_type(4)));

__device__ __forceinline__ float fast_tanh(float x){
  float cx = fminf(fmaxf(x, -10.f), 10.f);
  float e = __expf(2.f*cx);
  return 1.f - 2.f*__builtin_amdgcn_rcpf(e + 1.f);
}

// LDS-only block barrier: does NOT drain vmcnt (global stores stay in flight).
__device__ __forceinline__ void block_sync_lds(){
  asm volatile("s_waitcnt lgkmcnt(0)\n\ts_barrier" ::: "memory");
}

__device__ __forceinline__ bool has_sent(u32x4 d){
  return (((d.x & 0xFFFFu)==0xFFFFu) || ((d.x>>16)==0xFFFFu) ||
          ((d.y & 0xFFFFu)==0xFFFFu) || ((d.y>>16)==0xFFFFu) ||
          ((d.z & 0xFFFFu)==0xFFFFu) || ((d.z>>16)==0xFFFFu) ||
          ((d.w & 0xFFFFu)==0xFFFFu) || ((d.w>>16)==0xFFFFu));
}

// ---- fill rG (4 MiB = 1,048,576 dwords) with fp16 sentinel 0xFFFF ----
__global__ void fill_sentinel(unsigned* p){
  p[blockIdx.x*256u + threadIdx.x] = 0xFFFFFFFFu;
}

// ---- pre2[h][t][b] = NOISE_STD*noise[t][b][h] + TAU*(u@w_in^T + b_in)[b][h] ----
__global__ void pre_kernel(const float* __restrict__ u, const float* __restrict__ noise,
                           const float* __restrict__ w_in_w, const float* __restrict__ w_in_b,
                           float* __restrict__ pre2){
  int F = blockIdx.x*256 + threadIdx.x;      // < 2097152, enumerated [t][h][b]
  int b = F & 15; int h = (F>>4) & 255; int t = F >> 12;
  const float* up = u + (b*512 + t)*8;
  const float* wp = w_in_w + h*8;
  float s = w_in_b[h];
  #pragma unroll
  for (int i = 0; i < 8; ++i) s += up[i]*wp[i];
  pre2[h*8192 + t*16 + b] = NOISE_STD*noise[t*4096 + b*256 + h] + TAU*s;
}

// ---- swizzle w_hh (fp32 [i][j][k]) into fp16 MFMA-B-fragment order ----
// uint4 index = ((i*4 + wv)*32 + jtl*8 + ks)*64 + lane, element e in 0..7
// B[k][n=j]: j = (wv*4+jtl)*16 + (lane&15), k = ks*32 + (lane>>4)*8 + e
__global__ void wsw_kernel(const float* __restrict__ w_hh, __half* __restrict__ wsw){
  int F = blockIdx.x*256 + threadIdx.x;      // < 16777216
  int e = F & 7, lane = (F>>3)&63, ks = (F>>9)&7, jtl = (F>>12)&3, wv = (F>>14)&3, i = F>>16;
  int j = (wv*4 + jtl)*16 + (lane & 15);
  int k = ks*32 + (lane>>4)*8 + e;
  wsw[F] = __float2half(w_hh[(i<<16) | (j<<8) | k]);
}

// ---- persistent recurrence kernel: 256 blocks x 256 threads, cooperative ----
__global__ void __launch_bounds__(256, 1) rnn_kernel(
    const float* __restrict__ x0, const float* __restrict__ pre2, const __half* __restrict__ wsw,
    __half* rG, float* __restrict__ traj, float* __restrict__ xlast)
{
  __shared__ alignas(16) unsigned short r_lds[16*264];  // r[b][k] fp16 bits, stride 264
  __shared__ alignas(16) float pre_lds[8192];           // pre2 slice [t][b_own]
  __shared__ float red[64];

  const int tid = threadIdx.x;
  const int bid = blockIdx.x;                      // = i
  const int wv = tid >> 6, lane = tid & 63;
  const int q = lane >> 4, col = lane & 15;

  // ---- load W[i] fragments into registers once (32KB per wave) ----
  uint4 wreg[4][8];
  {
    const uint4* gw = (const uint4*)wsw + (size_t)(bid*4 + wv)*32*64 + lane;
    #pragma unroll
    for (int jtl = 0; jtl < 4; ++jtl)
      #pragma unroll
      for (int ks = 0; ks < 8; ++ks)
        wreg[jtl][ks] = gw[(jtl*8 + ks)*64];
  }

  // ---- pre slice (512 steps x 16 b = 32KB) -> LDS, fully coalesced ----
  {
    const float4* ps = (const float4*)(pre2 + bid*8192);
    float4* pl = (float4*)pre_lds;
    #pragma unroll
    for (int c = 0; c < 8; ++c) pl[c*256 + tid] = ps[c*256 + tid];
  }

  // ---- init: x slice in registers (lanes 0..15), r_0 in LDS ----
  float xreg = 0.f;
  if (tid < 16) xreg = x0[tid*256 + bid];
  #pragma unroll
  for (int c = 0; c < 16; ++c)
    r_lds[c*264 + tid] = __half_as_ushort(__float2half(fast_tanh(x0[c*256 + tid])));
  __syncthreads();

  const int p = tid - 128;                         // poller chunk id (waves 2-3)

  #pragma unroll 1
  for (int t = 0; t < 512; ++t){
    // ---- stage 1: tmp[b][j] = sum_k W[i][j][k] r[b][k]  (all waves) ----
    f32x4 acc[4] = {{0.f,0.f,0.f,0.f},{0.f,0.f,0.f,0.f},{0.f,0.f,0.f,0.f},{0.f,0.f,0.f,0.f}};
    #pragma unroll
    for (int ks = 0; ks < 8; ++ks){
      f16x8 A = *(const f16x8*)(r_lds + col*264 + ks*32 + q*8);   // A[b=col][k-frag]
      #pragma unroll
      for (int jtl = 0; jtl < 4; ++jtl){
        union { uint4 u; f16x8 v; } wu; wu.u = wreg[jtl][ks];
        acc[jtl] = __builtin_amdgcn_mfma_f32_16x16x32_f16(A, wu.v, acc[jtl], 0, 0, 0);
      }
    }

    // ---- stage 2: rec[b] partial = sum_j r[b][j]*tmp[b][j] ----
    // D layout: col(j) = lane&15, row(b) = q*4 + reg
    float s[4] = {0.f, 0.f, 0.f, 0.f};
    #pragma unroll
    for (int jtl = 0; jtl < 4; ++jtl){
      int j = (wv*4 + jtl)*16 + col;
      #pragma unroll
      for (int reg = 0; reg < 4; ++reg)
        s[reg] += acc[jtl][reg] * __half2float(__ushort_as_half(r_lds[(q*4 + reg)*264 + j]));
    }
    #pragma unroll
    for (int off = 1; off < 16; off <<= 1){
      #pragma unroll
      for (int reg = 0; reg < 4; ++reg) s[reg] += __shfl_xor(s[reg], off, 64);
    }
    if (col == 0){
      #pragma unroll
      for (int reg = 0; reg < 4; ++reg) red[wv*16 + q*4 + reg] = s[reg];
    }
    block_sync_lds();

    // ---- wave0 owners: update x, publish r fp16 (32B line), traj fp32 ----
    if (tid < 16){
      float rec = red[tid] + red[16 + tid] + red[32 + tid] + red[48 + tid];
      float xn = xreg + TAU*(rec - xreg) + pre_lds[t*16 + tid];
      xreg = xn;
      unsigned rv = (unsigned)__half_as_ushort(__float2half(fast_tanh(xn)));
      asm volatile("global_store_short %0, %1, off sc0 sc1"
                   :: "v"(rG + (size_t)t*4096 + bid*16 + tid), "v"(rv) : "memory");
      traj[(size_t)tid*131072 + t*256 + bid] = xn;   // fp32, fire-and-forget
    }

    // ---- waves 2-3: poll slot t (data-as-flag, loads-only vmcnt) ----
    if (p >= 0 && t < 511){
      const __half* cp = rG + (size_t)t*4096 + p*32;  // 64B: i=2p,2p+1 x b=0..15
      u32x4 d0, d1, d2, d3;
      __builtin_amdgcn_s_sleep(4);                    // skip the guaranteed-miss sweep
      for (;;){
        asm volatile("global_load_dwordx4 %0, %4, off sc0 sc1\n\t"
                     "global_load_dwordx4 %1, %4, off offset:16 sc0 sc1\n\t"
                     "global_load_dwordx4 %2, %4, off offset:32 sc0 sc1\n\t"
                     "global_load_dwordx4 %3, %4, off offset:48 sc0 sc1\n\t"
                     "s_waitcnt vmcnt(0)"
                     : "=&v"(d0), "=&v"(d1), "=&v"(d2), "=&v"(d3)
                     : "v"(cp) : "memory");
        if (!(has_sent(d0) || has_sent(d1) || has_sent(d2) || has_sent(d3))) break;
        __builtin_amdgcn_s_sleep(1);
      }
      // transpose: r_lds[b][i] ; thread owns dword column p (i=2p low, 2p+1 high)
      union { u32x4 v[2]; unsigned short h[16]; } U0, U1;
      U0.v[0] = d0; U0.v[1] = d1; U1.v[0] = d2; U1.v[1] = d3;
      unsigned* rl = (unsigned*)r_lds;
      #pragma unroll
      for (int b = 0; b < 16; ++b)
        rl[b*132 + p] = (unsigned)U0.h[b] | ((unsigned)U1.h[b] << 16);
    }
    block_sync_lds();
  }
  if (tid < 16) xlast[tid*256 + bid] = xreg;
}

// ---- out[b][t][o] = sum_h tanh(traj[b][t][h]) * w_out_w[o][h] + w_out_b[o] ----
__global__ void out_kernel(const float* __restrict__ traj, const float* __restrict__ w_out_w,
                           const float* __restrict__ w_out_b, float* __restrict__ out){
  __shared__ float wo[2048];
  int tid = threadIdx.x;
  #pragma unroll
  for (int c = 0; c < 8; ++c) wo[c*256 + tid] = w_out_w[c*256 + tid];
  __syncthreads();
  int wv = tid >> 6, lane = tid & 63;
  int p = blockIdx.x*4 + wv;                 // p = b*512 + t, < 8192
  float4 v = *(const float4*)&traj[(size_t)p*256 + lane*4];
  float th0 = fast_tanh(v.x), th1 = fast_tanh(v.y), th2 = fast_tanh(v.z), th3 = fast_tanh(v.w);
  #pragma unroll
  for (int o = 0; o < 8; ++o){
    const float* w = &wo[o*256 + lane*4];
    float s = th0*w[0] + th1*w[1] + th2*w[2] + th3*w[3];
    #pragma unroll
    for (int off = 32; off > 0; off >>= 1) s += __shfl_xor(s, off, 64);
    if (lane == 0) out[(size_t)p*8 + o] = s + w_out_b[o];
  }
}

extern "C" void kernel_launch(void* const* d_in, const int* in_sizes, int n_in,
                              void* d_out, int out_size, void* d_ws, size_t ws_size,
                              hipStream_t stream){
  const float* u       = (const float*)d_in[0];
  const float* x0      = (const float*)d_in[1];
  const float* noise   = (const float*)d_in[2];
  const float* w_hh    = (const float*)d_in[3];
  const float* w_in_w  = (const float*)d_in[4];
  const float* w_in_b  = (const float*)d_in[5];
  const float* w_out_w = (const float*)d_in[6];
  const float* w_out_b = (const float*)d_in[7];

  float* out   = (float*)d_out;          // [16][512][8]   = 65536
  float* xlast = out + 65536;            // [16][256]      = 4096
  float* traj  = xlast + 4096;           // [16][512][256] = 2097152

  uint8_t* ws = (uint8_t*)d_ws;
  __half* rG   = (__half*)ws;                          // 4 MiB: 512 slots x [i][b] fp16
  float*  pre2 = (float*)(ws + 4194304);               // 8 MiB: [h][t][b]
  __half* wsw  = (__half*)(ws + 4194304 + 8388608);    // 32 MiB swizzled W (fp16)

  fill_sentinel<<<4096, 256, 0, stream>>>((unsigned*)rG);
  pre_kernel<<<8192, 256, 0, stream>>>(u, noise, w_in_w, w_in_b, pre2);
  wsw_kernel<<<65536, 256, 0, stream>>>(w_hh, wsw);
  {
    void* args[] = {(void*)&x0, (void*)&pre2, (void*)&wsw,
                    (void*)&rG, (void*)&traj, (void*)&xlast};
    hipLaunchCooperativeKernel((const void*)rnn_kernel, dim3(256), dim3(256),
                               args, 0, stream);
  }
  out_kernel<<<2048, 256, 0, stream>>>(traj, w_out_w, w_out_b, out);
}